// Round 8
// baseline (204.947 us; speedup 1.0000x reference)
//
#include <hip/hip_runtime.h>

#define NEG_SLOPE 0.2f
#define NBMAX 256   // max coarse buckets (n <= 65536)

typedef __attribute__((ext_vector_type(8))) short bf16x8;
typedef __attribute__((ext_vector_type(16))) float f32x16;

__device__ inline ushort bf16rne(float f) {
  uint u = __float_as_uint(f);
  u += 0x7fff + ((u >> 16) & 1);
  return (ushort)(u >> 16);
}
__device__ inline float bf2f(ushort h) { return __uint_as_float((uint)h << 16); }

// XOR swizzle within a 256B LDS row: spreads 16B slots across banks
#define XS(row, byte) ((byte) ^ (((row) & 15) << 4))

// ---------------- prep: W[k][n] fp32 -> Wt_hi/Wt_lo bf16 [n][k] ----------------
__global__ __launch_bounds__(256) void splitW(const float* __restrict__ W,
    ushort* __restrict__ Wh, ushort* __restrict__ Wl) {
  int i = blockIdx.x * 256 + threadIdx.x;     // 16384 elements
  int k = i >> 7, nn = i & 127;
  float w = W[i];
  ushort h = bf16rne(w);
  float lo = w - bf2f(h);
  Wh[nn * 128 + k] = h;
  Wl[nn * 128 + k] = bf16rne(lo);
}

// ---------------- MFMA GEMM: C[n,128] = A[n,128] @ W[128,128] ----------------
// hi/lo bf16 split (3 mfma per k-step) for fp32-grade accuracy.
__global__ __launch_bounds__(256) void gemm_mfma(const float* __restrict__ A,
    const ushort* __restrict__ Wh, const ushort* __restrict__ Wl,
    float* __restrict__ C, ushort* __restrict__ Cb, int n) {
  __shared__ __align__(16) ushort sAh[64 * 128];
  __shared__ __align__(16) ushort sAl[64 * 128];
  __shared__ __align__(16) ushort sBh[64 * 128];
  __shared__ __align__(16) ushort sBl[64 * 128];
  const int t = threadIdx.x;
  const int row0 = blockIdx.x * 64;
  const int col0 = blockIdx.y * 64;
  for (int i = t; i < 2048; i += 256) {
    int r = i >> 5, c4 = i & 31;
    int gr = row0 + r;
    float4 v = make_float4(0.f, 0.f, 0.f, 0.f);
    if (gr < n) v = ((const float4*)(A + (size_t)gr * 128))[c4];
    ushort4 h, l;
    h.x = bf16rne(v.x); l.x = bf16rne(v.x - bf2f(h.x));
    h.y = bf16rne(v.y); l.y = bf16rne(v.y - bf2f(h.y));
    h.z = bf16rne(v.z); l.z = bf16rne(v.z - bf2f(h.z));
    h.w = bf16rne(v.w); l.w = bf16rne(v.w - bf2f(h.w));
    int byte = XS(r, r * 256 + c4 * 8);
    *(ushort4*)((char*)sAh + byte) = h;
    *(ushort4*)((char*)sAl + byte) = l;
  }
  for (int i = t; i < 1024; i += 256) {
    int r = i >> 4, q = i & 15;
    int byte = XS(r, r * 256 + q * 16);
    *(uint4*)((char*)sBh + byte) = ((const uint4*)(Wh + (size_t)(col0 + r) * 128))[q];
    *(uint4*)((char*)sBl + byte) = ((const uint4*)(Wl + (size_t)(col0 + r) * 128))[q];
  }
  __syncthreads();
  const int w = t >> 6, lane = t & 63;
  const int rbase = (w >> 1) * 32;
  const int cbase = (w & 1) * 32;
  const int lr = lane & 31;
  const int hi = lane >> 5;
  const int arow = rbase + lr;
  const int brow = cbase + lr;
  f32x16 acc0 = {};
  f32x16 acc1 = {};
#pragma unroll
  for (int ks = 0; ks < 8; ++ks) {
    int kb = (ks * 16 + hi * 8) * 2;
    bf16x8 ah = *(bf16x8*)((char*)sAh + XS(arow, arow * 256 + kb));
    bf16x8 al = *(bf16x8*)((char*)sAl + XS(arow, arow * 256 + kb));
    bf16x8 bh = *(bf16x8*)((char*)sBh + XS(brow, brow * 256 + kb));
    bf16x8 bl = *(bf16x8*)((char*)sBl + XS(brow, brow * 256 + kb));
    if (ks & 1) {
      acc1 = __builtin_amdgcn_mfma_f32_32x32x16_bf16(ah, bh, acc1, 0, 0, 0);
      acc1 = __builtin_amdgcn_mfma_f32_32x32x16_bf16(ah, bl, acc1, 0, 0, 0);
      acc1 = __builtin_amdgcn_mfma_f32_32x32x16_bf16(al, bh, acc1, 0, 0, 0);
    } else {
      acc0 = __builtin_amdgcn_mfma_f32_32x32x16_bf16(ah, bh, acc0, 0, 0, 0);
      acc0 = __builtin_amdgcn_mfma_f32_32x32x16_bf16(ah, bl, acc0, 0, 0, 0);
      acc0 = __builtin_amdgcn_mfma_f32_32x32x16_bf16(al, bh, acc0, 0, 0, 0);
    }
  }
  const int gcol = col0 + cbase + lr;
#pragma unroll
  for (int r = 0; r < 16; ++r) {
    int grow = row0 + rbase + (r & 3) + 8 * (r >> 2) + 4 * hi;
    if (grow < n) {
      float v = acc0[r] + acc1[r];
      C[(size_t)grow * 128 + gcol] = v;
      Cb[(size_t)grow * 128 + gcol] = bf16rne(v);
    }
  }
}

// ---------------- per-node attention logits (from fp32 feat) ----------------
__global__ __launch_bounds__(256) void node_attn4(const float* __restrict__ feat,
    const float* __restrict__ attn_l, const float* __restrict__ attn_r,
    float* __restrict__ el, float* __restrict__ er, int n4) {
  int i = blockIdx.x * 256 + threadIdx.x;
  if (i >= n4) return;
  const int h = i & 3;
  const float* f = feat + (size_t)i * 32;
  const float* al = attn_l + h * 32;
  const float* ar = attn_r + h * 32;
  float sl = 0.f, sr = 0.f;
#pragma unroll
  for (int k = 0; k < 32; k += 4) {
    float4 v = *(const float4*)(f + k);
    float4 a = *(const float4*)(al + k);
    float4 b = *(const float4*)(ar + k);
    sl += v.x * a.x + v.y * a.y + v.z * a.z + v.w * a.w;
    sr += v.x * b.x + v.y * b.y + v.z * b.z + v.w * b.w;
  }
  el[i] = sl;
  er[i] = sr;
}

__global__ __launch_bounds__(256) void node_attn1(const float* __restrict__ feat,
    const float* __restrict__ attn_l, const float* __restrict__ attn_r,
    float* __restrict__ el, float* __restrict__ er, int n) {
  int i = blockIdx.x * 256 + threadIdx.x;
  if (i >= n) return;
  const float* f = feat + (size_t)i * 128;
  float sl = 0.f, sr = 0.f;
#pragma unroll 8
  for (int k = 0; k < 128; k += 4) {
    float4 v = *(const float4*)(f + k);
    float4 a = *(const float4*)(attn_l + k);
    float4 b = *(const float4*)(attn_r + k);
    sl += v.x * a.x + v.y * a.y + v.z * a.z + v.w * a.w;
    sr += v.x * b.x + v.y * b.y + v.z * b.z + v.w * b.w;
  }
  el[i] = sl;
  er[i] = sr;
}

// ---------------- CSR build via two-level bucket sort ----------------
__global__ __launch_bounds__(1024) void bucket_count(const int* __restrict__ dst,
    int* __restrict__ bucketCount, int E_) {
  __shared__ int h[NBMAX];
  const int t = threadIdx.x;
  if (t < NBMAX) h[t] = 0;
  __syncthreads();
  const int base = blockIdx.x * 4096;
#pragma unroll
  for (int k = 0; k < 4; ++k) {
    int i = base + k * 1024 + t;
    if (i < E_) atomicAdd(&h[dst[i] >> 8], 1);
  }
  __syncthreads();
  if (t < NBMAX && h[t]) atomicAdd(&bucketCount[t], h[t]);
}

__global__ __launch_bounds__(256) void bucket_scan(const int* __restrict__ bucketCount,
    int* __restrict__ bucketOff, int* __restrict__ bucketCursor,
    int* __restrict__ rowptr, int nb, int n, int E_) {
  __shared__ int s[256];
  const int t = threadIdx.x;
  int v = (t < nb) ? bucketCount[t] : 0;
  s[t] = v;
  __syncthreads();
  for (int off = 1; off < 256; off <<= 1) {
    int u = (t >= off) ? s[t - off] : 0;
    __syncthreads();
    s[t] += u;
    __syncthreads();
  }
  int excl = s[t] - v;
  if (t < nb) { bucketOff[t] = excl; bucketCursor[t] = excl; }
  if (t == nb - 1) { bucketOff[nb] = s[t]; rowptr[n] = E_; }
}

__global__ __launch_bounds__(1024) void bucket_scatter(const int* __restrict__ src,
    const int* __restrict__ dst, int* __restrict__ bucketCursor,
    uint* __restrict__ bucketData, int E_) {
  __shared__ int h[NBMAX];
  __shared__ int bse[NBMAX];
  const int t = threadIdx.x;
  if (t < NBMAX) h[t] = 0;
  __syncthreads();
  const int base = blockIdx.x * 4096;
  int sv[4], dv[4], bk[4];
  bool ok[4];
#pragma unroll
  for (int k = 0; k < 4; ++k) {
    int i = base + k * 1024 + t;
    ok[k] = i < E_;
    if (ok[k]) {
      sv[k] = src[i];
      dv[k] = dst[i];
      bk[k] = dv[k] >> 8;
      atomicAdd(&h[bk[k]], 1);
    }
  }
  __syncthreads();
  if (t < NBMAX) {
    int c = h[t];
    bse[t] = c ? atomicAdd(&bucketCursor[t], c) : 0;
    h[t] = 0;
  }
  __syncthreads();
#pragma unroll
  for (int k = 0; k < 4; ++k) {
    if (ok[k]) {
      int r = atomicAdd(&h[bk[k]], 1);
      bucketData[bse[bk[k]] + r] = (uint)sv[k] | ((uint)(dv[k] & 255) << 16);
    }
  }
}

// one block per coarse bucket; csr entry packed: src(16) | node(16)<<16
__global__ __launch_bounds__(1024) void fine_csr(const uint* __restrict__ bucketData,
    const int* __restrict__ bucketOff, int* __restrict__ rowptr,
    uint* __restrict__ csr, int n) {
  __shared__ int fh[256];
  __shared__ int fx[256];
  const int b = blockIdx.x;
  const int t = threadIdx.x;
  const int beg = bucketOff[b];
  const int cnt = bucketOff[b + 1] - beg;
  if (t < 256) fh[t] = 0;
  __syncthreads();
  for (int i = t; i < cnt; i += 1024) atomicAdd(&fh[bucketData[beg + i] >> 16], 1);
  __syncthreads();
  if (t < 256) fx[t] = fh[t];
  __syncthreads();
  for (int off = 1; off < 256; off <<= 1) {
    int u = 0;
    if (t < 256 && t >= off) u = fx[t - off];
    __syncthreads();
    if (t < 256) fx[t] += u;
    __syncthreads();
  }
  if (t < 256) {
    int excl = fx[t] - fh[t];
    int node = b * 256 + t;
    if (node < n) rowptr[node] = beg + excl;
    fh[t] = excl;
  }
  __syncthreads();
  const uint nodeBase = (uint)b << 8;
  for (int i = t; i < cnt; i += 1024) {
    uint rec = bucketData[beg + i];
    int r = atomicAdd(&fh[rec >> 16], 1);
    csr[beg + r] = (rec & 0xffffu) | ((nodeBase + (rec >> 16)) << 16);
  }
}

// ---------------- per-edge softmax weights in CSR order (L2-resident el/er) --------
__global__ __launch_bounds__(256) void edge_w4(const uint* __restrict__ csr,
    const float* __restrict__ el, const float* __restrict__ er,
    float* __restrict__ w4, int E_) {
  int i = blockIdx.x * 256 + threadIdx.x;
  if (i >= E_) return;
  uint rec = csr[i];
  int s = rec & 0xffffu, d = rec >> 16;
  float4 l = ((const float4*)el)[s];
  float4 r = ((const float4*)er)[d];
  float e;
  float4 w;
  e = l.x + r.x; e = e > 0.f ? e : NEG_SLOPE * e; w.x = __expf(e);
  e = l.y + r.y; e = e > 0.f ? e : NEG_SLOPE * e; w.y = __expf(e);
  e = l.z + r.z; e = e > 0.f ? e : NEG_SLOPE * e; w.z = __expf(e);
  e = l.w + r.w; e = e > 0.f ? e : NEG_SLOPE * e; w.w = __expf(e);
  ((float4*)w4)[i] = w;
}

__global__ __launch_bounds__(256) void edge_w1(const uint* __restrict__ csr,
    const float* __restrict__ el, const float* __restrict__ er,
    float* __restrict__ w1, int E_) {
  int i = blockIdx.x * 256 + threadIdx.x;
  if (i >= E_) return;
  uint rec = csr[i];
  float e = el[rec & 0xffffu] + er[rec >> 16];
  e = e > 0.f ? e : NEG_SLOPE * e;
  w1[i] = __expf(e);
}

// ---------------- aggregation (bf16 gather, precomputed w, 4x MLP unroll) ----------
__global__ __launch_bounds__(256) void aggregate4(const int* __restrict__ rowptr,
    const uint* __restrict__ csr, const ushort* __restrict__ featb,
    const float* __restrict__ w4f, const float* __restrict__ bias,
    float* __restrict__ out, int n) {
  int node = blockIdx.x * 4 + (threadIdx.x >> 6);
  if (node >= n) return;
  const int lane = threadIdx.x & 63;
  const int f0 = lane * 2;
  const int h = lane >> 4;
  float a0 = 0.f, a1 = 0.f, d = 0.f;
  const int beg = rowptr[node], end = rowptr[node + 1];
  int idx = beg;
  for (; idx + 3 < end; idx += 4) {
    uint r0 = csr[idx + 0];
    uint r1 = csr[idx + 1];
    uint r2 = csr[idx + 2];
    uint r3 = csr[idx + 3];
    float w0 = w4f[(idx + 0) * 4 + h];
    float w1 = w4f[(idx + 1) * 4 + h];
    float w2 = w4f[(idx + 2) * 4 + h];
    float w3 = w4f[(idx + 3) * 4 + h];
    uint v0 = *(const uint*)(featb + (size_t)(r0 & 0xffffu) * 128 + f0);
    uint v1 = *(const uint*)(featb + (size_t)(r1 & 0xffffu) * 128 + f0);
    uint v2 = *(const uint*)(featb + (size_t)(r2 & 0xffffu) * 128 + f0);
    uint v3 = *(const uint*)(featb + (size_t)(r3 & 0xffffu) * 128 + f0);
    a0 += __uint_as_float(v0 << 16) * w0; a1 += __uint_as_float(v0 & 0xffff0000u) * w0;
    a0 += __uint_as_float(v1 << 16) * w1; a1 += __uint_as_float(v1 & 0xffff0000u) * w1;
    a0 += __uint_as_float(v2 << 16) * w2; a1 += __uint_as_float(v2 & 0xffff0000u) * w2;
    a0 += __uint_as_float(v3 << 16) * w3; a1 += __uint_as_float(v3 & 0xffff0000u) * w3;
    d += w0 + w1 + w2 + w3;
  }
  for (; idx < end; ++idx) {
    uint r = csr[idx];
    float w = w4f[idx * 4 + h];
    uint v = *(const uint*)(featb + (size_t)(r & 0xffffu) * 128 + f0);
    a0 += __uint_as_float(v << 16) * w;
    a1 += __uint_as_float(v & 0xffff0000u) * w;
    d += w;
  }
  float inv = d > 0.f ? 1.f / d : 0.f;
  float v0 = a0 * inv + bias[f0];
  v0 = v0 > 0.f ? v0 : __expf(v0) - 1.f;   // ELU
  float v1 = a1 * inv + bias[f0 + 1];
  v1 = v1 > 0.f ? v1 : __expf(v1) - 1.f;
  *(float2*)(out + (size_t)node * 128 + f0) = make_float2(v0, v1);
}

__global__ __launch_bounds__(256) void aggregate1(const int* __restrict__ rowptr,
    const uint* __restrict__ csr, const ushort* __restrict__ featb,
    const float* __restrict__ w1f, const float* __restrict__ bias,
    float* __restrict__ out, int n) {
  int node = blockIdx.x * 4 + (threadIdx.x >> 6);
  if (node >= n) return;
  const int lane = threadIdx.x & 63;
  const int f0 = lane * 2;
  float a0 = 0.f, a1 = 0.f, d = 0.f;
  const int beg = rowptr[node], end = rowptr[node + 1];
  int idx = beg;
  for (; idx + 3 < end; idx += 4) {
    uint r0 = csr[idx + 0];
    uint r1 = csr[idx + 1];
    uint r2 = csr[idx + 2];
    uint r3 = csr[idx + 3];
    float w0 = w1f[idx + 0];
    float w1 = w1f[idx + 1];
    float w2 = w1f[idx + 2];
    float w3 = w1f[idx + 3];
    uint v0 = *(const uint*)(featb + (size_t)(r0 & 0xffffu) * 128 + f0);
    uint v1 = *(const uint*)(featb + (size_t)(r1 & 0xffffu) * 128 + f0);
    uint v2 = *(const uint*)(featb + (size_t)(r2 & 0xffffu) * 128 + f0);
    uint v3 = *(const uint*)(featb + (size_t)(r3 & 0xffffu) * 128 + f0);
    a0 += __uint_as_float(v0 << 16) * w0; a1 += __uint_as_float(v0 & 0xffff0000u) * w0;
    a0 += __uint_as_float(v1 << 16) * w1; a1 += __uint_as_float(v1 & 0xffff0000u) * w1;
    a0 += __uint_as_float(v2 << 16) * w2; a1 += __uint_as_float(v2 & 0xffff0000u) * w2;
    a0 += __uint_as_float(v3 << 16) * w3; a1 += __uint_as_float(v3 & 0xffff0000u) * w3;
    d += w0 + w1 + w2 + w3;
  }
  for (; idx < end; ++idx) {
    uint r = csr[idx];
    float w = w1f[idx];
    uint v = *(const uint*)(featb + (size_t)(r & 0xffffu) * 128 + f0);
    a0 += __uint_as_float(v << 16) * w;
    a1 += __uint_as_float(v & 0xffff0000u) * w;
    d += w;
  }
  float inv = d > 0.f ? 1.f / d : 0.f;
  float v0 = a0 * inv + bias[f0];
  v0 = v0 > 0.f ? v0 : __expf(v0) - 1.f;
  float v1 = a1 * inv + bias[f0 + 1];
  v1 = v1 > 0.f ? v1 : __expf(v1) - 1.f;
  *(float2*)(out + (size_t)node * 128 + f0) = make_float2(v0, v1);
}

// ---------------- launch ----------------
extern "C" void kernel_launch(void* const* d_in, const int* in_sizes, int n_in,
                              void* d_out, int out_size, void* d_ws, size_t ws_size,
                              hipStream_t stream) {
  const float* x   = (const float*)d_in[0];
  const int*   src = (const int*)d_in[1];
  const int*   dst = (const int*)d_in[2];
  const float* W0  = (const float*)d_in[3];
  const float* al0 = (const float*)d_in[4];
  const float* ar0 = (const float*)d_in[5];
  const float* b0  = (const float*)d_in[6];
  const float* W1  = (const float*)d_in[7];
  const float* al1 = (const float*)d_in[8];
  const float* ar1 = (const float*)d_in[9];
  const float* b1  = (const float*)d_in[10];
  float* out = (float*)d_out;
  const int n  = in_sizes[0] / 128;
  const int E_ = in_sizes[1];

  char* p = (char*)d_ws;
  auto alloc = [&](size_t bytes) {
    char* r = p;
    p += (bytes + 255) & ~(size_t)255;
    return r;
  };
  float*  feat0  = (float*)alloc((size_t)n * 128 * 4);
  ushort* feat0b = (ushort*)alloc((size_t)n * 128 * 2);
  float*  h0     = (float*)alloc((size_t)n * 128 * 4);
  float*  feat1  = (float*)alloc((size_t)n * 128 * 4);
  ushort* feat1b = (ushort*)alloc((size_t)n * 128 * 2);
  float* el0   = (float*)alloc((size_t)n * 4 * 4);
  float* er0   = (float*)alloc((size_t)n * 4 * 4);
  float* el1   = (float*)alloc((size_t)n * 4);
  float* er1   = (float*)alloc((size_t)n * 4);
  int* rowptr  = (int*)alloc((size_t)(n + 1) * 4);
  uint* csr    = (uint*)alloc((size_t)E_ * 4);
  uint* bucketData  = (uint*)alloc((size_t)E_ * 4);
  int* bucketCount  = (int*)alloc(NBMAX * 4);
  int* bucketOff    = (int*)alloc((NBMAX + 1) * 4);
  int* bucketCursor = (int*)alloc(NBMAX * 4);
  ushort* W0h = (ushort*)alloc(128 * 128 * 2);
  ushort* W0l = (ushort*)alloc(128 * 128 * 2);
  ushort* W1h = (ushort*)alloc(128 * 128 * 2);
  ushort* W1l = (ushort*)alloc(128 * 128 * 2);
  // overlays: w4 lives in feat1 (dead until layer-1 gemm); w1 in feat0 (dead after node_attn4)
  float* w4 = feat1;    // E*4 floats  (12.8 MB <= 25.6 MB)
  float* w1 = feat0;    // E   floats  ( 3.2 MB <= 25.6 MB)

  const int nbk = (n + 255) >> 8;
  const int gb  = (E_ + 4095) / 4096;
  const int eb  = (E_ + 255) / 256;

  hipMemsetAsync(bucketCount, 0, NBMAX * 4, stream);

  // weight prep (tiny)
  splitW<<<64, 256, 0, stream>>>(W0, W0h, W0l);
  splitW<<<64, 256, 0, stream>>>(W1, W1h, W1l);

  // CSR build (graph shared by both layers)
  bucket_count<<<gb, 1024, 0, stream>>>(dst, bucketCount, E_);
  bucket_scan<<<1, 256, 0, stream>>>(bucketCount, bucketOff, bucketCursor, rowptr, nbk, n, E_);
  bucket_scatter<<<gb, 1024, 0, stream>>>(src, dst, bucketCursor, bucketData, E_);
  fine_csr<<<nbk, 1024, 0, stream>>>(bucketData, bucketOff, rowptr, csr, n);

  dim3 gg((n + 63) / 64, 2);

  // layer 0
  gemm_mfma<<<gg, 256, 0, stream>>>(x, W0h, W0l, feat0, feat0b, n);
  node_attn4<<<(n * 4 + 255) / 256, 256, 0, stream>>>(feat0, al0, ar0, el0, er0, n * 4);
  edge_w4<<<eb, 256, 0, stream>>>(csr, el0, er0, w4, E_);
  aggregate4<<<(n + 3) / 4, 256, 0, stream>>>(rowptr, csr, feat0b, w4, b0, h0, n);

  // layer 1
  gemm_mfma<<<gg, 256, 0, stream>>>(h0, W1h, W1l, feat1, feat1b, n);
  node_attn1<<<(n + 255) / 256, 256, 0, stream>>>(feat1, al1, ar1, el1, er1, n);
  edge_w1<<<eb, 256, 0, stream>>>(csr, el1, er1, w1, E_);
  aggregate1<<<(n + 3) / 4, 256, 0, stream>>>(rowptr, csr, feat1b, w1, b1, out, n);
}